// Round 8
// baseline (879.974 us; speedup 1.0000x reference)
//
#include <hip/hip_runtime.h>
#include <cstdint>
#include <cstddef>

#define E_TOT 32768
#define HD    512
#define NR    3
#define EPAD_MAX 33536          // E_TOT + 3*256
#define NBLK  262               // (EPAD_MAX/256) * 2 N-tiles

typedef __attribute__((ext_vector_type(8))) short short8;
typedef __attribute__((ext_vector_type(4))) float f32x4;

static __device__ __forceinline__ unsigned short f2bf(float f) {
  union { float f; unsigned int u; } x; x.f = f;
  unsigned int u = x.u;
  return (unsigned short)((u + 0x7fffu + ((u >> 16) & 1u)) >> 16);  // RNE
}

static __device__ __forceinline__ void gload_lds16(const void* g, void* l) {
  __builtin_amdgcn_global_load_lds(
      (const __attribute__((address_space(1))) unsigned int*)g,
      (__attribute__((address_space(3))) unsigned int*)l, 16, 0, 0);
}

// bijective chunked XCD swizzle (m204), NWG=262: q=32, r=6
static __device__ __forceinline__ int chunk_swz(int bid) {
  const int x = bid & 7, i = bid >> 3;
  return (x < 6) ? x * 33 + i : 198 + (x - 6) * 32 + i;
}

// ---------------- prep kernels ----------------

#define AL256(x) (((x) + 255) & ~255)

__global__ void k_sort1(const int* __restrict__ roles, int* __restrict__ ctrl) {
  __shared__ int cnt[NR];
  const int t = threadIdx.x;
  if (t < NR) cnt[t] = 0;
  __syncthreads();
  int c0 = 0, c1 = 0, c2 = 0;
  for (int i = t; i < E_TOT; i += 1024) {
    const int ro = roles[i];
    c0 += (ro == 0); c1 += (ro == 1); c2 += (ro == 2);
  }
  if (c0) atomicAdd(&cnt[0], c0);
  if (c1) atomicAdd(&cnt[1], c1);
  if (c2) atomicAdd(&cnt[2], c2);
  __syncthreads();
  if (t == 0) {
    const int off1 = AL256(cnt[0]);
    const int off2 = AL256(off1 + cnt[1]);
    const int ptot = AL256(off2 + cnt[2]);
    ctrl[0] = cnt[0]; ctrl[1] = cnt[1]; ctrl[2] = cnt[2];
    ctrl[4] = 0; ctrl[5] = off1; ctrl[6] = off2; ctrl[7] = ptot;
    ctrl[9] = 0; ctrl[10] = off1; ctrl[11] = off2;
  }
}

__global__ void k_scatter(const int* __restrict__ roles, int* __restrict__ ctrl,
                          int* __restrict__ perm) {
  int e = blockIdx.x * 256 + threadIdx.x;
  int lane = threadIdx.x & 63;
  int role = roles[e];
#pragma unroll
  for (int r = 0; r < NR; ++r) {
    unsigned long long m = __ballot(role == r);
    if (!m) continue;
    int leader = __ffsll((unsigned long long)m) - 1;
    int base = 0;
    if (lane == leader) base = atomicAdd(&ctrl[9 + r], (int)__popcll(m));
    base = __shfl(base, leader);
    if (role == r) {
      int rank = (int)__popcll(m & ((1ull << lane) - 1ull));
      perm[base + rank] = e;
    }
  }
}

// fill pad slots (through EPAD_MAX for the last role, so k_gather is safe)
__global__ void k_padfill(const int* __restrict__ ctrl, int* __restrict__ perm) {
#pragma unroll
  for (int r = 0; r < NR; ++r) {
    const int start = ctrl[4 + r] + ctrl[r];
    const int end = (r < 2) ? ctrl[5 + r] : EPAD_MAX;
    const int fill = (ctrl[r] > 0) ? perm[ctrl[4 + r]] : 0;
    for (int i = start + (int)threadIdx.x; i < end; i += 256) perm[i] = fill;
  }
}

__global__ void k_convw(const float* __restrict__ W, const float* __restrict__ U,
                        const float* __restrict__ P1, const float* __restrict__ P2,
                        const int* __restrict__ dlayer, short* __restrict__ dst) {
  const int per = NR * HD * HD;
  const int which = blockIdx.y;
  const float* src = (which == 0) ? W : (which == 1) ? U : (which == 2) ? P1 : P2;
  src += (size_t)dlayer[0] * per;
  short* d = dst + (size_t)which * per;
  int i = (blockIdx.x * 256 + threadIdx.x) * 4;
  if (i >= per) return;
  float4 v = *(const float4*)(src + i);
  short4 o;
  o.x = (short)f2bf(v.x); o.y = (short)f2bf(v.y);
  o.z = (short)f2bf(v.z); o.w = (short)f2bf(v.w);
  *(short4*)(d + i) = o;
}

// gather-by-perm + convert to bf16, sorted+padded rows (64 threads per row)
__global__ void k_gather(const float* __restrict__ v, const float* __restrict__ r,
                         const int* __restrict__ perm,
                         short* __restrict__ vbf, short* __restrict__ rbf) {
  const int idx = blockIdx.x * 256 + threadIdx.x;   // EPAD_MAX*64 threads
  const int row = idx >> 6;
  const int kc = (idx & 63) << 3;
  const int g = perm[row];
  const float4* pv = (const float4*)(v + (size_t)g * HD + kc);
  const float4* pr = (const float4*)(r + (size_t)g * HD + kc);
  const float4 a0 = pv[0], a1 = pv[1];
  const float4 b0 = pr[0], b1 = pr[1];
  short8 sa, sb;
#pragma unroll
  for (int j = 0; j < 4; ++j) {
    sa[j] = (short)f2bf(((const float*)&a0)[j]);
    sa[4 + j] = (short)f2bf(((const float*)&a1)[j]);
    sb[j] = (short)f2bf(((const float*)&b0)[j]);
    sb[4 + j] = (short)f2bf(((const float*)&b1)[j]);
  }
  *(short8*)(vbf + (size_t)row * HD + kc) = sa;
  *(short8*)(rbf + (size_t)row * HD + kc) = sb;
}

// ---------------- pipelined GEMMs ----------------
// Common geometry: BM=BN=256, BK=32, 512 thr = 8 waves (2M x 4N),
// wave tile 128x64. LDS unit = short8 (16B); per region 1024 units
// (256 rows x 4 units). XOR swizzle u' = u ^ ((row>>1)&3): source
// pre-swizzled on gload (linear dest), read XOR'd -> 2-way max (free, m136).
// Counted vmcnt (T4): B prefetch distance 2 tiles, A distance 1; never
// drain to 0 mid-loop. D-frag: col=lane&15, row=(lane>>4)*4+reg [m89/m91].

#define TAIL(ACC, FA, FB, MI0)                                                 \
  __builtin_amdgcn_s_barrier();                                                \
  asm volatile("s_waitcnt lgkmcnt(0)" ::: "memory");                           \
  __builtin_amdgcn_sched_barrier(0);                                           \
  __builtin_amdgcn_s_setprio(1);                                               \
  _Pragma("unroll") for (int mi = 0; mi < 4; ++mi)                             \
    _Pragma("unroll") for (int ni = 0; ni < 4; ++ni)                           \
      ACC[(MI0) + mi][ni] = __builtin_amdgcn_mfma_f32_16x16x32_bf16(           \
          FA[(MI0) + mi], FB[ni], ACC[(MI0) + mi][ni], 0, 0, 0);               \
  __builtin_amdgcn_s_setprio(0);                                               \
  __builtin_amdgcn_s_barrier();

#define RD(dst, base, bi, ROW)                                                 \
  { const int rr_ = (ROW); dst = L[bi][(base) + rr_ * 4 + (ku ^ ((rr_ >> 1) & 3))]; }

#define ST(dstbase, bi, srcP, rowbase, K0)                                     \
  _Pragma("unroll") for (int j = 0; j < 2; ++j)                                \
    gload_lds16((srcP) + (size_t)((rowbase) + srow[j]) * HD + (K0) + soff[j],  \
                &L[bi][(dstbase) + j * 512 + tid]);

// S1: h = (vbf@W^T + wb) * (rbf@U^T + ub) -> bf16 (sorted). 128KB LDS, dbuf.
// Slot: [Av 0..1023][Ar 1024..2047][BW 2048..3071][BU 3072..4095]
__global__ __launch_bounds__(512, 2) void k_dual(
    const short* __restrict__ vbf, const short* __restrict__ rbf,
    const short* __restrict__ Wall, const short* __restrict__ Uall,
    const float* __restrict__ Wb, const float* __restrict__ Ub,
    const int* __restrict__ dlayer, const int* __restrict__ ctrl,
    short* __restrict__ hout) {
  __shared__ short8 L[2][4096];

  const int lb = chunk_swz(blockIdx.x);
  const int m0 = (lb >> 1) * 256, n0 = (lb & 1) * 256;
  if (m0 >= ctrl[7]) return;
  const int role = (m0 >= ctrl[6]) ? 2 : (m0 >= ctrl[5] ? 1 : 0);

  const int tid = threadIdx.x, lane = tid & 63, wv = tid >> 6;
  const int wr = wv >> 2, wc = wv & 3, krow = lane & 15, ku = lane >> 4;

  const short* BWp = Wall + (size_t)role * HD * HD;
  const short* BUp = Uall + (size_t)role * HD * HD;

  int srow[2], soff[2];
#pragma unroll
  for (int j = 0; j < 2; ++j) {
    srow[j] = j * 128 + (tid >> 2);
    soff[j] = ((tid & 3) ^ ((srow[j] >> 1) & 3)) * 8;
  }

  f32x4 accv[8][4], accr[8][4];
#pragma unroll
  for (int a = 0; a < 8; ++a)
#pragma unroll
    for (int b = 0; b < 4; ++b) { accv[a][b] = (f32x4)0.f; accr[a][b] = (f32x4)0.f; }
  short8 fa[8], fbw[4], fbu[4];

  // prologue: tile0 full -> slot0; B(1) -> slot1
  ST(0,    0, vbf, m0, 0)
  ST(1024, 0, rbf, m0, 0)
  ST(2048, 0, BWp, n0, 0)
  ST(3072, 0, BUp, n0, 0)
  ST(2048, 1, BWp, n0, 32)
  ST(3072, 1, BUp, n0, 32)
  asm volatile("s_waitcnt vmcnt(4)" ::: "memory");
  __builtin_amdgcn_s_barrier();

  int cur = 0;
  for (int t = 0; t < 16; ++t) {
    const int nxt = cur ^ 1;
    const int kA = (t + 1) * 32, kB = (t + 2) * 32;

    // P0: BW-frags + Av lo; issue Av(t+1)
#pragma unroll
    for (int ni = 0; ni < 4; ++ni) RD(fbw[ni], 2048, cur, wc * 64 + ni * 16 + krow)
#pragma unroll
    for (int mi = 0; mi < 4; ++mi) RD(fa[mi], 0, cur, wr * 128 + mi * 16 + krow)
    if (t < 15) { ST(0, nxt, vbf, m0, kA) }
    TAIL(accv, fa, fbw, 0)

    // P1: Av hi; issue Ar(t+1)
#pragma unroll
    for (int mi = 4; mi < 8; ++mi) RD(fa[mi], 0, cur, wr * 128 + mi * 16 + krow)
    if (t < 15) { ST(1024, nxt, rbf, m0, kA) }
    TAIL(accv, fa, fbw, 4)

    // P2: BU-frags + Ar lo; issue BW(t+2) into cur (BW dead after P0)
#pragma unroll
    for (int ni = 0; ni < 4; ++ni) RD(fbu[ni], 3072, cur, wc * 64 + ni * 16 + krow)
#pragma unroll
    for (int mi = 0; mi < 4; ++mi) RD(fa[mi], 1024, cur, wr * 128 + mi * 16 + krow)
    if (t < 14) { ST(2048, cur, BWp, n0, kB) }
    TAIL(accr, fa, fbu, 0)

    // P3: Ar hi; issue BU(t+2); counted gate
#pragma unroll
    for (int mi = 4; mi < 8; ++mi) RD(fa[mi], 1024, cur, wr * 128 + mi * 16 + krow)
    if (t < 14) {
      ST(3072, cur, BUp, n0, kB)
      asm volatile("s_waitcnt vmcnt(4)" ::: "memory");
    } else {
      asm volatile("s_waitcnt vmcnt(0)" ::: "memory");
    }
    TAIL(accr, fa, fbu, 4)

    cur = nxt;
  }

  const int ld = dlayer[0];
  const float* wb = Wb + ((size_t)ld * NR + role) * HD + n0;
  const float* ub = Ub + ((size_t)ld * NR + role) * HD + n0;
#pragma unroll
  for (int ni = 0; ni < 4; ++ni) {
    const int col = wc * 64 + ni * 16 + krow;
    const float bw_ = wb[col];
    const float bu_ = ub[col];
#pragma unroll
    for (int mi = 0; mi < 8; ++mi) {
      const int rbase = m0 + wr * 128 + mi * 16 + ku * 4;
#pragma unroll
      for (int j = 0; j < 4; ++j) {
        const float hval = (accv[mi][ni][j] + bw_) * (accr[mi][ni][j] + bu_);
        hout[(size_t)(rbase + j) * HD + n0 + col] = (short)f2bf(hval);
      }
    }
  }
}

// S2 (OUTM 1): tb = relu(h@P1^T + b1) -> bf16. S3 (OUTM 2): out[perm] = tb@P2^T + b2.
// 64KB LDS dbuf -> 2 blocks/CU. Slot: [A 0..1023][B 1024..2047]
template <int OUTM>
__global__ __launch_bounds__(512, 4) void k_single(
    const short* __restrict__ A, const short* __restrict__ B,
    const float* __restrict__ biasAll, const int* __restrict__ dlayer,
    const int* __restrict__ ctrl, const int* __restrict__ perm,
    short* __restrict__ outS, float* __restrict__ outF) {
  __shared__ short8 L[2][2048];

  const int lb = chunk_swz(blockIdx.x);
  const int m0 = (lb >> 1) * 256, n0 = (lb & 1) * 256;
  if (m0 >= ctrl[7]) return;
  const int role = (m0 >= ctrl[6]) ? 2 : (m0 >= ctrl[5] ? 1 : 0);

  const int tid = threadIdx.x, lane = tid & 63, wv = tid >> 6;
  const int wr = wv >> 2, wc = wv & 3, krow = lane & 15, ku = lane >> 4;

  const short* Bp = B + (size_t)role * HD * HD;

  int srow[2], soff[2];
#pragma unroll
  for (int j = 0; j < 2; ++j) {
    srow[j] = j * 128 + (tid >> 2);
    soff[j] = ((tid & 3) ^ ((srow[j] >> 1) & 3)) * 8;
  }

  f32x4 acc[8][4];
#pragma unroll
  for (int a = 0; a < 8; ++a)
#pragma unroll
    for (int b = 0; b < 4; ++b) acc[a][b] = (f32x4)0.f;
  short8 fa[8], fb[4];

  ST(0,    0, A,  m0, 0)
  ST(1024, 0, Bp, n0, 0)
  ST(1024, 1, Bp, n0, 32)
  asm volatile("s_waitcnt vmcnt(2)" ::: "memory");
  __builtin_amdgcn_s_barrier();

  int cur = 0;
  for (int t = 0; t < 16; ++t) {
    const int nxt = cur ^ 1;
    const int kA = (t + 1) * 32, kB = (t + 2) * 32;

    // P0: B-frags + A lo; issue A(t+1)
#pragma unroll
    for (int ni = 0; ni < 4; ++ni) RD(fb[ni], 1024, cur, wc * 64 + ni * 16 + krow)
#pragma unroll
    for (int mi = 0; mi < 4; ++mi) RD(fa[mi], 0, cur, wr * 128 + mi * 16 + krow)
    if (t < 15) { ST(0, nxt, A, m0, kA) }
    TAIL(acc, fa, fb, 0)

    // P1: A hi; issue B(t+2) into cur; counted gate
#pragma unroll
    for (int mi = 4; mi < 8; ++mi) RD(fa[mi], 0, cur, wr * 128 + mi * 16 + krow)
    if (t < 14) {
      ST(1024, cur, Bp, n0, kB)
      asm volatile("s_waitcnt vmcnt(2)" ::: "memory");
    } else {
      asm volatile("s_waitcnt vmcnt(0)" ::: "memory");
    }
    TAIL(acc, fa, fb, 4)

    cur = nxt;
  }

  const int ld = dlayer[0];
  const float* bias = biasAll + ((size_t)ld * NR + role) * HD + n0;

  int pg[8][4];
  if constexpr (OUTM == 2) {
#pragma unroll
    for (int mi = 0; mi < 8; ++mi)
#pragma unroll
      for (int j = 0; j < 4; ++j)
        pg[mi][j] = perm[m0 + wr * 128 + mi * 16 + ku * 4 + j];
  }

#pragma unroll
  for (int ni = 0; ni < 4; ++ni) {
    const int col = wc * 64 + ni * 16 + krow;
    const float b = bias[col];
#pragma unroll
    for (int mi = 0; mi < 8; ++mi) {
      const int rbase = m0 + wr * 128 + mi * 16 + ku * 4;
#pragma unroll
      for (int j = 0; j < 4; ++j) {
        float val = acc[mi][ni][j] + b;
        if constexpr (OUTM == 1) {
          val = fmaxf(val, 0.f);
          outS[(size_t)(rbase + j) * HD + n0 + col] = (short)f2bf(val);
        } else {
          outF[(size_t)pg[mi][j] * HD + n0 + col] = val;
        }
      }
    }
  }
}

// ---------------- launch ----------------

extern "C" void kernel_launch(void* const* d_in, const int* in_sizes, int n_in,
                              void* d_out, int out_size, void* d_ws, size_t ws_size,
                              hipStream_t stream) {
  const float* v    = (const float*)d_in[0];
  const float* r    = (const float*)d_in[1];
  const int*   rol  = (const int*)d_in[2];
  const float* W    = (const float*)d_in[3];
  const float* Wb   = (const float*)d_in[4];
  const float* U    = (const float*)d_in[5];
  const float* Ub   = (const float*)d_in[6];
  const float* P1   = (const float*)d_in[7];
  const float* P1b  = (const float*)d_in[8];
  const float* P2   = (const float*)d_in[9];
  const float* P2b  = (const float*)d_in[10];
  const int*   dly  = (const int*)d_in[11];

  char* ws = (char*)d_ws;
  int* ctrl = (int*)ws;                          // 256 B
  int* perm = (int*)(ws + 256);                  // EPAD_MAX ints -> 134,400
  short* Wbf = (short*)(ws + 134400);            // 4 x NR*HD*HD bf16
  short* Ubf  = Wbf + (size_t)NR * HD * HD;
  short* P1bf = Ubf + (size_t)NR * HD * HD;
  short* P2bf = P1bf + (size_t)NR * HD * HD;     // ends 6,425,856
  short* vbf = (short*)(ws + 6425856);           // EPAD_MAX*HD bf16 (sorted)
  short* rbf = vbf + (size_t)EPAD_MAX * HD;      // ends 75,107,584 (R5-proven ws bound)
  short* tb  = vbf;                              // alias: vbf dead after k_dual
  short* h   = (short*)d_out;                    // front 34.3MB of d_out (dead before S3)
  float* out = (float*)d_out;

  k_sort1<<<1, 1024, 0, stream>>>(rol, ctrl);
  k_scatter<<<E_TOT / 256, 256, 0, stream>>>(rol, ctrl, perm);
  k_padfill<<<1, 256, 0, stream>>>(ctrl, perm);
  k_convw<<<dim3((NR * HD * HD) / 4 / 256, 4, 1), 256, 0, stream>>>(W, U, P1, P2, dly, Wbf);
  k_gather<<<EPAD_MAX * 64 / 256, 256, 0, stream>>>(v, r, perm, vbf, rbf);

  k_dual<<<NBLK, 512, 0, stream>>>(vbf, rbf, Wbf, Ubf, Wb, Ub, dly, ctrl, h);
  k_single<1><<<NBLK, 512, 0, stream>>>(h, P1bf, P1b, dly, ctrl, perm, tb, nullptr);
  k_single<2><<<NBLK, 512, 0, stream>>>(tb, P2bf, P2b, dly, ctrl, perm, nullptr, out);

  (void)in_sizes; (void)n_in; (void)out_size; (void)ws_size;
}